// Round 16
// baseline (105.787 us; speedup 1.0000x reference)
//
#include <hip/hip_runtime.h>
#include <math.h>

#define BATCH 32
#define MROWS 120
#define JDIM  64
#define DIM   512
#define NROW  (BATCH * MROWS)   // 3840

#define LOGIT_SCALE 14.285714285714283f

typedef float  f4     __attribute__((ext_vector_type(4)));
typedef float  f32x4  __attribute__((ext_vector_type(4)));
typedef short  bf16x8 __attribute__((ext_vector_type(8)));
typedef unsigned short u16x4 __attribute__((ext_vector_type(4)));

static __device__ __forceinline__ unsigned short f2bf(float f) {
    unsigned int u = __float_as_uint(f);
    u += 0x7FFFu + ((u >> 16) & 1u);
    return (unsigned short)(u >> 16);
}

// ---------------------------------------------------------------------------
// K1 (R14 structure, SINGLE CHANGE: LB(256,4) -> LB(256,8) = 32 waves/CU).
// fused skel mean+norm (NT stream) + text norm; one block per (b,m).
// ---------------------------------------------------------------------------
__global__ __launch_bounds__(256, 8) void k_skel_text(
    const float* __restrict__ skel_in, const float* __restrict__ text,
    unsigned short* __restrict__ skel_bf, unsigned short* __restrict__ text_bf)
{
    const int row = blockIdx.x;          // b*120 + m
    const int t   = threadIdx.x;         // 0..255
    const int wid = t >> 6, lane = t & 63;

    f4 tv = (f4){0.f, 0.f, 0.f, 0.f};
    if (t < 128) tv = ((const f4*)(text + (size_t)row * DIM))[t];

    const f4* __restrict__ base =
        (const f4*)(skel_in + (size_t)row * (JDIM * DIM)) + wid * 2048 + lane;

    f4 acc0 = (f4){0.f, 0.f, 0.f, 0.f};
    f4 acc1 = (f4){0.f, 0.f, 0.f, 0.f};
    #pragma unroll 16
    for (int it2 = 0; it2 < 16; ++it2) {
        f4 a = __builtin_nontemporal_load(&base[it2 * 128]);
        f4 b = __builtin_nontemporal_load(&base[it2 * 128 + 64]);
        acc0 += a;
        acc1 += b;
    }

    __shared__ f4 lds[4][128];
    lds[wid][lane]      = acc0;
    lds[wid][lane + 64] = acc1;
    __syncthreads();

    f4 acc = (f4){0.f, 0.f, 0.f, 0.f};
    float ss = 0.f;
    if (t < 128) {
        acc = lds[0][t] + lds[1][t] + lds[2][t] + lds[3][t];
        ss = acc.x * acc.x + acc.y * acc.y + acc.z * acc.z + acc.w * acc.w;
    }

    #pragma unroll
    for (int o = 32; o > 0; o >>= 1) ss += __shfl_xor(ss, o, 64);
    __shared__ float wsum[2];
    if (t < 128 && lane == 0) wsum[wid] = ss;
    __syncthreads();
    const float inv = 1.0f / sqrtf(wsum[0] + wsum[1]);

    if (t < 128) {
        u16x4 o;
        o.x = f2bf(acc.x * inv);
        o.y = f2bf(acc.y * inv);
        o.z = f2bf(acc.z * inv);
        o.w = f2bf(acc.w * inv);
        *(u16x4*)(skel_bf + (size_t)row * DIM + 4 * t) = o;
    }

    float sst = tv.x * tv.x + tv.y * tv.y + tv.z * tv.z + tv.w * tv.w;
    #pragma unroll
    for (int o = 32; o > 0; o >>= 1) sst += __shfl_xor(sst, o, 64);
    __shared__ float tsum[2];
    if (t < 128 && lane == 0) tsum[wid] = sst;
    __syncthreads();

    if (t < 128) {
        const float sc = LOGIT_SCALE / sqrtf(tsum[0] + tsum[1]);
        u16x4 o;
        o.x = f2bf(tv.x * sc);
        o.y = f2bf(tv.y * sc);
        o.z = f2bf(tv.z * sc);
        o.w = f2bf(tv.w * sc);
        *(u16x4*)(text_bf + (size_t)row * DIM + 4 * t) = o;
    }
}

// ---------------------------------------------------------------------------
// K2 (FROZEN, R14): column-split x2. 512 single-wave blocks, blk=(b,w,half).
// 4 col-tiles of mfma_f32_16x16x32_bf16; per-row partial LSE + diagonal.
// C/D layout: col=lane&15, row=(lane>>4)*4+reg.
// ---------------------------------------------------------------------------
__global__ __launch_bounds__(64) void k_logits_mfma(
    const unsigned short* __restrict__ text_bf,
    const unsigned short* __restrict__ skel_bf,
    float* __restrict__ part_mx, float* __restrict__ part_se,
    float* __restrict__ diag)
{
    const int blk = blockIdx.x;          // b*16 + w*2 + h
    const int b   = blk >> 4;
    const int w   = (blk >> 1) & 7;
    const int h   = blk & 1;
    const int l   = threadIdx.x;         // 0..63
    const int cl  = l & 15;
    const int cg  = l >> 4;

    const int arow = 16 * w + cl;
    const bool a_ok = (arow < MROWS);
    const unsigned short* __restrict__ ta =
        text_bf + ((size_t)b * MROWS + arow) * DIM;
    const unsigned short* __restrict__ sb =
        skel_bf + (size_t)b * MROWS * DIM;

    const bf16x8 zerov = (bf16x8){0,0,0,0,0,0,0,0};

    f32x4 acc[4];
    #pragma unroll
    for (int i = 0; i < 4; ++i) acc[i] = (f32x4){0.f, 0.f, 0.f, 0.f};

    for (int ks = 0; ks < 16; ++ks) {
        const int k0 = ks * 32 + cg * 8;
        const bf16x8 a = a_ok ? *(const bf16x8*)(ta + k0) : zerov;
        #pragma unroll
        for (int tt = 0; tt < 4; ++tt) {
            const int n = 16 * (4 * h + tt) + cl;
            const bf16x8 bb = (n < MROWS)
                ? *(const bf16x8*)(sb + (size_t)n * DIM + k0) : zerov;
            acc[tt] = __builtin_amdgcn_mfma_f32_16x16x32_bf16(a, bb, acc[tt],
                                                              0, 0, 0);
        }
    }

    #pragma unroll
    for (int r = 0; r < 4; ++r) {
        const int row = 16 * w + 4 * cg + r;

        float mx = -INFINITY;
        #pragma unroll
        for (int tt = 0; tt < 4; ++tt)
            if (16 * (4 * h + tt) + cl < MROWS) mx = fmaxf(mx, acc[tt][r]);
        #pragma unroll
        for (int o = 1; o < 16; o <<= 1) mx = fmaxf(mx, __shfl_xor(mx, o, 16));

        float se = 0.f;
        #pragma unroll
        for (int tt = 0; tt < 4; ++tt)
            if (16 * (4 * h + tt) + cl < MROWS) se += expf(acc[tt][r] - mx);
        #pragma unroll
        for (int o = 1; o < 16; o <<= 1) se += __shfl_xor(se, o, 16);

        if (cl == 0) {
            part_mx[((size_t)b * 2 + h) * 128 + row] = mx;
            part_se[((size_t)b * 2 + h) * 128 + row] = se;
        }

        if ((w >> 2) == h && row < MROWS && cl == 4 * cg + r)
            diag[(size_t)b * 128 + row] = acc[w - 4 * h][r];
    }
}

// ---------------------------------------------------------------------------
// K3 (FROZEN, R14): combine 2 half-LSEs per (b,m); out = -mean(diag - lse).
// ---------------------------------------------------------------------------
__global__ __launch_bounds__(1024) void k_final(
    const float* __restrict__ part_mx, const float* __restrict__ part_se,
    const float* __restrict__ diag, float* __restrict__ out)
{
    const int t = threadIdx.x;
    const int wid = t >> 6, lane = t & 63;

    float sum = 0.f;
    #pragma unroll
    for (int k = 0; k < 4; ++k) {
        const int p = t + k * 1024;      // 0..4095
        const int b = p >> 7, m = p & 127;
        if (m < MROWS) {
            const float mx0 = part_mx[((size_t)b * 2 + 0) * 128 + m];
            const float mx1 = part_mx[((size_t)b * 2 + 1) * 128 + m];
            const float se0 = part_se[((size_t)b * 2 + 0) * 128 + m];
            const float se1 = part_se[((size_t)b * 2 + 1) * 128 + m];
            const float mx  = fmaxf(mx0, mx1);
            const float se  = se0 * expf(mx0 - mx) + se1 * expf(mx1 - mx);
            sum += diag[(size_t)b * 128 + m] - (mx + logf(se));
        }
    }

    #pragma unroll
    for (int o = 32; o > 0; o >>= 1) sum += __shfl_xor(sum, o, 64);
    __shared__ float wsum[16];
    if (lane == 0) wsum[wid] = sum;
    __syncthreads();
    if (t == 0) {
        float s = 0.f;
        #pragma unroll
        for (int i = 0; i < 16; ++i) s += wsum[i];
        out[0] = -s * (1.0f / (float)NROW);
    }
}

extern "C" void kernel_launch(void* const* d_in, const int* in_sizes, int n_in,
                              void* d_out, int out_size, void* d_ws, size_t ws_size,
                              hipStream_t stream)
{
    const float* skel_in = (const float*)d_in[0];   // (32,120,64,512) f32
    const float* text    = (const float*)d_in[1];   // (32,120,512)    f32
    float* out = (float*)d_out;

    unsigned short* skel_bf = (unsigned short*)d_ws;            // 3.93 MB
    unsigned short* text_bf = skel_bf + (size_t)NROW * DIM;     // 3.93 MB
    float* part_mx = (float*)(text_bf + (size_t)NROW * DIM);    // 32*2*128
    float* part_se = part_mx + (size_t)BATCH * 2 * 128;         // 32*2*128
    float* diag    = part_se + (size_t)BATCH * 2 * 128;         // 32*128

    k_skel_text  <<<NROW,       256, 0, stream>>>(skel_in, text, skel_bf, text_bf);
    k_logits_mfma<<<BATCH * 16,  64, 0, stream>>>(text_bf, skel_bf,
                                                  part_mx, part_se, diag);
    k_final      <<<1,         1024, 0, stream>>>(part_mx, part_se, diag, out);
}

// Round 17
// 103.650 us; speedup vs baseline: 1.0206x; 1.0206x over previous
//
#include <hip/hip_runtime.h>
#include <math.h>

#define BATCH 32
#define MROWS 120
#define JDIM  64
#define DIM   512
#define NROW  (BATCH * MROWS)   // 3840

#define LOGIT_SCALE 14.285714285714283f

typedef float  f4     __attribute__((ext_vector_type(4)));
typedef float  f32x4  __attribute__((ext_vector_type(4)));
typedef short  bf16x8 __attribute__((ext_vector_type(8)));
typedef unsigned short u16x4 __attribute__((ext_vector_type(4)));

static __device__ __forceinline__ unsigned short f2bf(float f) {
    unsigned int u = __float_as_uint(f);
    u += 0x7FFFu + ((u >> 16) & 1u);
    return (unsigned short)(u >> 16);
}

// ---------------------------------------------------------------------------
// K1 (BEST, R14): fused skel mean+norm (NT stream) + text norm.
// one block per (b,m); 256 threads; wave w reads contiguous 32 KB sub-slab
// with nontemporal loads; LB(256,4) = 16 waves/CU.
// Probe ledger: NT +9us; layout null; barrier null; persistent -1.5;
// 32w/CU -2. ~5.3 TB/s is this pattern's measured ceiling.
// ---------------------------------------------------------------------------
__global__ __launch_bounds__(256, 4) void k_skel_text(
    const float* __restrict__ skel_in, const float* __restrict__ text,
    unsigned short* __restrict__ skel_bf, unsigned short* __restrict__ text_bf)
{
    const int row = blockIdx.x;          // b*120 + m
    const int t   = threadIdx.x;         // 0..255
    const int wid = t >> 6, lane = t & 63;

    f4 tv = (f4){0.f, 0.f, 0.f, 0.f};
    if (t < 128) tv = ((const f4*)(text + (size_t)row * DIM))[t];

    const f4* __restrict__ base =
        (const f4*)(skel_in + (size_t)row * (JDIM * DIM)) + wid * 2048 + lane;

    f4 acc0 = (f4){0.f, 0.f, 0.f, 0.f};
    f4 acc1 = (f4){0.f, 0.f, 0.f, 0.f};
    #pragma unroll 16
    for (int it2 = 0; it2 < 16; ++it2) {
        f4 a = __builtin_nontemporal_load(&base[it2 * 128]);
        f4 b = __builtin_nontemporal_load(&base[it2 * 128 + 64]);
        acc0 += a;
        acc1 += b;
    }

    __shared__ f4 lds[4][128];
    lds[wid][lane]      = acc0;
    lds[wid][lane + 64] = acc1;
    __syncthreads();

    f4 acc = (f4){0.f, 0.f, 0.f, 0.f};
    float ss = 0.f;
    if (t < 128) {
        acc = lds[0][t] + lds[1][t] + lds[2][t] + lds[3][t];
        ss = acc.x * acc.x + acc.y * acc.y + acc.z * acc.z + acc.w * acc.w;
    }

    #pragma unroll
    for (int o = 32; o > 0; o >>= 1) ss += __shfl_xor(ss, o, 64);
    __shared__ float wsum[2];
    if (t < 128 && lane == 0) wsum[wid] = ss;
    __syncthreads();
    const float inv = 1.0f / sqrtf(wsum[0] + wsum[1]);

    if (t < 128) {
        u16x4 o;
        o.x = f2bf(acc.x * inv);
        o.y = f2bf(acc.y * inv);
        o.z = f2bf(acc.z * inv);
        o.w = f2bf(acc.w * inv);
        *(u16x4*)(skel_bf + (size_t)row * DIM + 4 * t) = o;
    }

    float sst = tv.x * tv.x + tv.y * tv.y + tv.z * tv.z + tv.w * tv.w;
    #pragma unroll
    for (int o = 32; o > 0; o >>= 1) sst += __shfl_xor(sst, o, 64);
    __shared__ float tsum[2];
    if (t < 128 && lane == 0) tsum[wid] = sst;
    __syncthreads();

    if (t < 128) {
        const float sc = LOGIT_SCALE / sqrtf(tsum[0] + tsum[1]);
        u16x4 o;
        o.x = f2bf(tv.x * sc);
        o.y = f2bf(tv.y * sc);
        o.z = f2bf(tv.z * sc);
        o.w = f2bf(tv.w * sc);
        *(u16x4*)(text_bf + (size_t)row * DIM + 4 * t) = o;
    }
}

// ---------------------------------------------------------------------------
// K2 (FROZEN, R14): column-split x2. 512 single-wave blocks, blk=(b,w,half).
// 4 col-tiles of mfma_f32_16x16x32_bf16; per-row partial LSE + diagonal.
// C/D layout: col=lane&15, row=(lane>>4)*4+reg.
// ---------------------------------------------------------------------------
__global__ __launch_bounds__(64) void k_logits_mfma(
    const unsigned short* __restrict__ text_bf,
    const unsigned short* __restrict__ skel_bf,
    float* __restrict__ part_mx, float* __restrict__ part_se,
    float* __restrict__ diag)
{
    const int blk = blockIdx.x;          // b*16 + w*2 + h
    const int b   = blk >> 4;
    const int w   = (blk >> 1) & 7;
    const int h   = blk & 1;
    const int l   = threadIdx.x;         // 0..63
    const int cl  = l & 15;
    const int cg  = l >> 4;

    const int arow = 16 * w + cl;
    const bool a_ok = (arow < MROWS);
    const unsigned short* __restrict__ ta =
        text_bf + ((size_t)b * MROWS + arow) * DIM;
    const unsigned short* __restrict__ sb =
        skel_bf + (size_t)b * MROWS * DIM;

    const bf16x8 zerov = (bf16x8){0,0,0,0,0,0,0,0};

    f32x4 acc[4];
    #pragma unroll
    for (int i = 0; i < 4; ++i) acc[i] = (f32x4){0.f, 0.f, 0.f, 0.f};

    for (int ks = 0; ks < 16; ++ks) {
        const int k0 = ks * 32 + cg * 8;
        const bf16x8 a = a_ok ? *(const bf16x8*)(ta + k0) : zerov;
        #pragma unroll
        for (int tt = 0; tt < 4; ++tt) {
            const int n = 16 * (4 * h + tt) + cl;
            const bf16x8 bb = (n < MROWS)
                ? *(const bf16x8*)(sb + (size_t)n * DIM + k0) : zerov;
            acc[tt] = __builtin_amdgcn_mfma_f32_16x16x32_bf16(a, bb, acc[tt],
                                                              0, 0, 0);
        }
    }

    #pragma unroll
    for (int r = 0; r < 4; ++r) {
        const int row = 16 * w + 4 * cg + r;

        float mx = -INFINITY;
        #pragma unroll
        for (int tt = 0; tt < 4; ++tt)
            if (16 * (4 * h + tt) + cl < MROWS) mx = fmaxf(mx, acc[tt][r]);
        #pragma unroll
        for (int o = 1; o < 16; o <<= 1) mx = fmaxf(mx, __shfl_xor(mx, o, 16));

        float se = 0.f;
        #pragma unroll
        for (int tt = 0; tt < 4; ++tt)
            if (16 * (4 * h + tt) + cl < MROWS) se += expf(acc[tt][r] - mx);
        #pragma unroll
        for (int o = 1; o < 16; o <<= 1) se += __shfl_xor(se, o, 16);

        if (cl == 0) {
            part_mx[((size_t)b * 2 + h) * 128 + row] = mx;
            part_se[((size_t)b * 2 + h) * 128 + row] = se;
        }

        if ((w >> 2) == h && row < MROWS && cl == 4 * cg + r)
            diag[(size_t)b * 128 + row] = acc[w - 4 * h][r];
    }
}

// ---------------------------------------------------------------------------
// K3 (FROZEN, R14): combine 2 half-LSEs per (b,m); out = -mean(diag - lse).
// ---------------------------------------------------------------------------
__global__ __launch_bounds__(1024) void k_final(
    const float* __restrict__ part_mx, const float* __restrict__ part_se,
    const float* __restrict__ diag, float* __restrict__ out)
{
    const int t = threadIdx.x;
    const int wid = t >> 6, lane = t & 63;

    float sum = 0.f;
    #pragma unroll
    for (int k = 0; k < 4; ++k) {
        const int p = t + k * 1024;      // 0..4095
        const int b = p >> 7, m = p & 127;
        if (m < MROWS) {
            const float mx0 = part_mx[((size_t)b * 2 + 0) * 128 + m];
            const float mx1 = part_mx[((size_t)b * 2 + 1) * 128 + m];
            const float se0 = part_se[((size_t)b * 2 + 0) * 128 + m];
            const float se1 = part_se[((size_t)b * 2 + 1) * 128 + m];
            const float mx  = fmaxf(mx0, mx1);
            const float se  = se0 * expf(mx0 - mx) + se1 * expf(mx1 - mx);
            sum += diag[(size_t)b * 128 + m] - (mx + logf(se));
        }
    }

    #pragma unroll
    for (int o = 32; o > 0; o >>= 1) sum += __shfl_xor(sum, o, 64);
    __shared__ float wsum[16];
    if (lane == 0) wsum[wid] = sum;
    __syncthreads();
    if (t == 0) {
        float s = 0.f;
        #pragma unroll
        for (int i = 0; i < 16; ++i) s += wsum[i];
        out[0] = -s * (1.0f / (float)NROW);
    }
}

extern "C" void kernel_launch(void* const* d_in, const int* in_sizes, int n_in,
                              void* d_out, int out_size, void* d_ws, size_t ws_size,
                              hipStream_t stream)
{
    const float* skel_in = (const float*)d_in[0];   // (32,120,64,512) f32
    const float* text    = (const float*)d_in[1];   // (32,120,512)    f32
    float* out = (float*)d_out;

    unsigned short* skel_bf = (unsigned short*)d_ws;            // 3.93 MB
    unsigned short* text_bf = skel_bf + (size_t)NROW * DIM;     // 3.93 MB
    float* part_mx = (float*)(text_bf + (size_t)NROW * DIM);    // 32*2*128
    float* part_se = part_mx + (size_t)BATCH * 2 * 128;         // 32*2*128
    float* diag    = part_se + (size_t)BATCH * 2 * 128;         // 32*128

    k_skel_text  <<<NROW,       256, 0, stream>>>(skel_in, text, skel_bf, text_bf);
    k_logits_mfma<<<BATCH * 16,  64, 0, stream>>>(text_bf, skel_bf,
                                                  part_mx, part_se, diag);
    k_final      <<<1,         1024, 0, stream>>>(part_mx, part_se, diag, out);
}